// Round 17
// baseline (153.552 us; speedup 1.0000x reference)
//
#include <hip/hip_runtime.h>

// Scaled dot-product attention, B=2 H=12 S=2048 D=64, fp32 in/out.
// Outputs: out [B,H,S,D] then we [B,H,S,S] concatenated in d_out.
// R16 = R15 (best 143.8us: bf16 preconvert + R11 main) + STORE-EXEMPT
// in-loop barriers: __syncthreads emits s_waitcnt vmcnt(0) which drains
// the nt-store queue (~600-900cy HBM ack) every stage; the LDS dbuf only
// needs lgkmcnt(0)+s_barrier. nt stores now stay in flight across stages.

typedef short          s16x8 __attribute__((ext_vector_type(8)));
typedef unsigned short u16x8 __attribute__((ext_vector_type(8)));
typedef unsigned short u16x4 __attribute__((ext_vector_type(4)));
typedef float          f32x4 __attribute__((ext_vector_type(4)));

#define kS   2048
#define kD   64
#define kBH  24
#define OUT_ELEMS (kBH * kS * kD)     // 3145728
#define MASK_ELEMS (kS * kS)          // 4194304
#define CVT_TOTAL (2 * OUT_ELEMS + MASK_ELEMS)   // 10485760

static __device__ __forceinline__ unsigned short f2bf(float f) {
    union { float f; unsigned u; } x; x.f = f;
    return (unsigned short)((x.u + 0x7fffu + ((x.u >> 16) & 1u)) >> 16); // RNE
}
static __device__ __forceinline__ float bf2f(unsigned short v) {
    union { unsigned u; float f; } x; x.u = ((unsigned)v) << 16;
    return x.f;
}
static __device__ __forceinline__ u16x8 cvt8(const float4 f0, const float4 f1) {
    u16x8 r;
    r[0] = f2bf(f0.x); r[1] = f2bf(f0.y); r[2] = f2bf(f0.z); r[3] = f2bf(f0.w);
    r[4] = f2bf(f1.x); r[5] = f2bf(f1.y); r[6] = f2bf(f1.z); r[7] = f2bf(f1.w);
    return r;
}

// barrier that does NOT drain the vector-memory (store) queue:
// LDS ordering via lgkmcnt(0); nt stores stay in flight.
static __device__ __forceinline__ void lds_barrier() {
    asm volatile("s_waitcnt lgkmcnt(0)" ::: "memory");
    __builtin_amdgcn_s_barrier();
    asm volatile("" ::: "memory");
}

// ---------------- prologue: fp32 -> bf16 (K | V | mask) ----------------
__global__ __launch_bounds__(256)
void cvt_bf16(const float* __restrict__ K, const float* __restrict__ V,
              const float* __restrict__ M, unsigned short* __restrict__ W)
{
    const size_t e = ((size_t)blockIdx.x * 256 + threadIdx.x) * 8;
    if (e >= CVT_TOTAL) return;
    const float* src;
    size_t off;
    if (e < OUT_ELEMS)            { src = K; off = e; }
    else if (e < 2 * OUT_ELEMS)   { src = V; off = e - OUT_ELEMS; }
    else                          { src = M; off = e - 2 * OUT_ELEMS; }
    float4 a = *(const float4*)(src + off);
    float4 b = *(const float4*)(src + off + 4);
    *(u16x8*)(W + e) = cvt8(a, b);
}

// ---------------- main kernel (bf16 operands) ----------------
__global__ __launch_bounds__(256)
void attn_fused_b(const float* __restrict__ Qg, const unsigned short* __restrict__ Kb,
                  const unsigned short* __restrict__ Vb, const unsigned short* __restrict__ Mb,
                  float* __restrict__ Og, float* __restrict__ Wg)
{
    __shared__ __align__(16) unsigned short k_sh[2][32 * 64];
    __shared__ __align__(16) unsigned short vt_sh[2][64 * 32];
    __shared__ __align__(16) unsigned short p_sh[4][16 * 40];

    const int tid  = threadIdx.x;
    const int wv   = tid >> 6;
    const int lane = tid & 63;
    const int g    = lane >> 4;
    const int c    = lane & 15;

    // head-partitioned XCD swizzle (R11): 768 blocks, 96/XCD = 3 heads/XCD
    const int wg = ((int)blockIdx.x & 7) * 96 + ((int)blockIdx.x >> 3);
    const int bh = wg >> 5;
    const int qb = wg & 31;
    const int q0 = qb * 64 + wv * 16;

    // Q A-fragments (row = q0+c, k = h*32+g*8+j), validated R2
    s16x8 aQ[2];
    {
        const float* qp = Qg + ((size_t)(bh * kS + q0 + c)) * kD + g * 8;
        #pragma unroll
        for (int h = 0; h < 2; ++h) {
            float4 f0 = *(const float4*)(qp + h * 32);
            float4 f1 = *(const float4*)(qp + h * 32 + 4);
            union { u16x8 u; s16x8 s; } t; t.u = cvt8(f0, f1);
            aQ[h] = t.s;
        }
    }

    const int sr = tid >> 3;
    const int sc = (tid & 7) * 8;
    const unsigned short* kstage = Kb + ((size_t)bh * kS + sr) * kD + sc;
    const unsigned short* vstage = Vb + ((size_t)bh * kS + sr) * kD + sc;
    const unsigned kaddr_w = (unsigned)((sr * 128 + sc * 2) ^ ((sr & 7) << 4));
    const unsigned short* mrow = Mb + (size_t)(q0 + g * 4) * kS;

    // ================= pass 1: softmax denominators =================
    {
        *(u16x8*)((char*)k_sh[0] + kaddr_w) = *(const u16x8*)kstage;
    }
    __syncthreads();

    float sm[4] = {0.f, 0.f, 0.f, 0.f};
    int cur = 0;
    for (int t0 = 0; t0 < kS; t0 += 32) {
        const bool nxt = (t0 + 32) < kS;
        u16x8 kf;
        if (nxt) kf = *(const u16x8*)(kstage + (size_t)(t0 + 32) * kD);
        #pragma unroll
        for (int tt = 0; tt < 2; ++tt) {
            const int row = tt * 16 + c;
            f32x4 acc = {0.f, 0.f, 0.f, 0.f};
            #pragma unroll
            for (int h = 0; h < 2; ++h) {
                const unsigned a = (unsigned)((row * 128 + h * 64 + g * 16) ^ ((row & 7) << 4));
                s16x8 bK = *(const s16x8*)((const char*)k_sh[cur] + a);
                acc = __builtin_amdgcn_mfma_f32_16x16x32_bf16(aQ[h], bK, acc, 0, 0, 0);
            }
            const int t = t0 + tt * 16 + c;
            #pragma unroll
            for (int j = 0; j < 4; ++j)
                sm[j] += __expf(acc[j] * 0.125f + bf2f(mrow[(size_t)j * kS + t]));
        }
        if (nxt) {
            *(u16x8*)((char*)k_sh[cur ^ 1] + kaddr_w) = kf;
            lds_barrier();
            cur ^= 1;
        }
    }
    #pragma unroll
    for (int j = 0; j < 4; ++j) {
        float s = sm[j];
        s += __shfl_xor(s, 1);
        s += __shfl_xor(s, 2);
        s += __shfl_xor(s, 4);
        s += __shfl_xor(s, 8);
        sm[j] = 1.0f / s;
    }

    // ================= pass 2: write we, accumulate PV =================
    f32x4 accO[4];
    #pragma unroll
    for (int dt = 0; dt < 4; ++dt) accO[dt] = f32x4{0.f, 0.f, 0.f, 0.f};

    __syncthreads();
    {
        *(u16x8*)((char*)k_sh[0] + kaddr_w) = *(const u16x8*)kstage;
        u16x8 vb = *(const u16x8*)vstage;
        #pragma unroll
        for (int i = 0; i < 8; ++i) {
            const int d = sc + i;
            const unsigned b = (unsigned)((d * 64 + sr * 2) ^ (((d >> 3) & 7) << 4));
            *(unsigned short*)((char*)vt_sh[0] + b) = vb[i];
        }
    }
    __syncthreads();

    const int wr = lane >> 3;
    const int wcb = lane & 7;
    float* wbase = Wg + ((size_t)(bh * kS + q0)) * kS;

    cur = 0;
    for (int t0 = 0; t0 < kS; t0 += 32) {
        const bool nxt = (t0 + 32) < kS;
        u16x8 kf, vf;
        if (nxt) {
            kf = *(const u16x8*)(kstage + (size_t)(t0 + 32) * kD);
            vf = *(const u16x8*)(vstage + (size_t)(t0 + 32) * kD);
        }

        #pragma unroll
        for (int tt = 0; tt < 2; ++tt) {
            const int row = tt * 16 + c;
            f32x4 acc = {0.f, 0.f, 0.f, 0.f};
            #pragma unroll
            for (int h = 0; h < 2; ++h) {
                const unsigned a = (unsigned)((row * 128 + h * 64 + g * 16) ^ ((row & 7) << 4));
                s16x8 bK = *(const s16x8*)((const char*)k_sh[cur] + a);
                acc = __builtin_amdgcn_mfma_f32_16x16x32_bf16(aQ[h], bK, acc, 0, 0, 0);
            }
            const int t = t0 + tt * 16 + c;
            #pragma unroll
            for (int j = 0; j < 4; ++j) {
                const float p = __expf(acc[j] * 0.125f + bf2f(mrow[(size_t)j * kS + t])) * sm[j];
                p_sh[wv][(g * 4 + j) * 40 + tt * 16 + c] = f2bf(p);
            }
        }

        s16x8 pa = *(const s16x8*)((const char*)&p_sh[wv][0] + c * 80 + g * 16);
        #pragma unroll
        for (int dt = 0; dt < 4; ++dt) {
            const int d = dt * 16 + c;
            const unsigned b = (unsigned)((d * 64 + g * 16) ^ (((d >> 3) & 7) << 4));
            s16x8 bV = *(const s16x8*)((const char*)vt_sh[cur] + b);
            accO[dt] = __builtin_amdgcn_mfma_f32_16x16x32_bf16(pa, bV, accO[dt], 0, 0, 0);
        }

        // full-line we stores (R11): 8 adjacent lanes = one 128B line
        #pragma unroll
        for (int s = 0; s < 2; ++s) {
            const int row = wr + s * 8;
            u16x4 pb = *(const u16x4*)((const char*)&p_sh[wv][0] + row * 80 + wcb * 8);
            f32x4 w;
            #pragma unroll
            for (int i = 0; i < 4; ++i) w[i] = bf2f(pb[i]);
            __builtin_nontemporal_store(w, (f32x4*)(wbase + (size_t)row * kS + t0 + wcb * 4));
        }

        if (nxt) {
            *(u16x8*)((char*)k_sh[cur ^ 1] + kaddr_w) = kf;
            #pragma unroll
            for (int i = 0; i < 8; ++i) {
                const int d = sc + i;
                const unsigned b = (unsigned)((d * 64 + sr * 2) ^ (((d >> 3) & 7) << 4));
                *(unsigned short*)((char*)vt_sh[cur ^ 1] + b) = vf[i];
            }
            lds_barrier();   // nt stores stay in flight across the stage
            cur ^= 1;
        }
    }

    float* orow = Og + ((size_t)(bh * kS + q0 + g * 4)) * kD + c;
    #pragma unroll
    for (int dt = 0; dt < 4; ++dt) {
        #pragma unroll
        for (int j = 0; j < 4; ++j)
            __builtin_nontemporal_store(accO[dt][j], orow + (size_t)j * kD + dt * 16);
    }
}

// ---------------- fallback: exact R11 (fp32 operands) ----------------
__global__ __launch_bounds__(256)
void attn_fused_f32(const float* __restrict__ Qg, const float* __restrict__ Kg,
                    const float* __restrict__ Vg, const float* __restrict__ Mg,
                    float* __restrict__ Og, float* __restrict__ Wg)
{
    __shared__ __align__(16) unsigned short k_sh[2][32 * 64];
    __shared__ __align__(16) unsigned short vt_sh[2][64 * 32];
    __shared__ __align__(16) unsigned short p_sh[4][16 * 40];

    const int tid  = threadIdx.x;
    const int wv   = tid >> 6;
    const int lane = tid & 63;
    const int g    = lane >> 4;
    const int c    = lane & 15;

    const int wg = ((int)blockIdx.x & 7) * 96 + ((int)blockIdx.x >> 3);
    const int bh = wg >> 5;
    const int qb = wg & 31;
    const int q0 = qb * 64 + wv * 16;

    s16x8 aQ[2];
    {
        const float* qp = Qg + ((size_t)(bh * kS + q0 + c)) * kD + g * 8;
        #pragma unroll
        for (int h = 0; h < 2; ++h) {
            float4 f0 = *(const float4*)(qp + h * 32);
            float4 f1 = *(const float4*)(qp + h * 32 + 4);
            union { u16x8 u; s16x8 s; } t; t.u = cvt8(f0, f1);
            aQ[h] = t.s;
        }
    }

    const int sr = tid >> 3;
    const int sc = (tid & 7) * 8;
    const float* kstage = Kg + ((size_t)bh * kS + sr) * kD + sc;
    const float* vstage = Vg + ((size_t)bh * kS + sr) * kD + sc;
    const unsigned kaddr_w = (unsigned)((sr * 128 + sc * 2) ^ ((sr & 7) << 4));
    const float* mrow = Mg + (size_t)(q0 + g * 4) * kS;

    {
        *(u16x8*)((char*)k_sh[0] + kaddr_w) = cvt8(*(const float4*)kstage, *(const float4*)(kstage + 4));
    }
    __syncthreads();

    float sm[4] = {0.f, 0.f, 0.f, 0.f};
    int cur = 0;
    for (int t0 = 0; t0 < kS; t0 += 32) {
        const bool nxt = (t0 + 32) < kS;
        float4 kf0, kf1;
        if (nxt) {
            const float* src = kstage + (size_t)(t0 + 32) * kD;
            kf0 = *(const float4*)src; kf1 = *(const float4*)(src + 4);
        }
        #pragma unroll
        for (int tt = 0; tt < 2; ++tt) {
            const int row = tt * 16 + c;
            f32x4 acc = {0.f, 0.f, 0.f, 0.f};
            #pragma unroll
            for (int h = 0; h < 2; ++h) {
                const unsigned a = (unsigned)((row * 128 + h * 64 + g * 16) ^ ((row & 7) << 4));
                s16x8 bK = *(const s16x8*)((const char*)k_sh[cur] + a);
                acc = __builtin_amdgcn_mfma_f32_16x16x32_bf16(aQ[h], bK, acc, 0, 0, 0);
            }
            const int t = t0 + tt * 16 + c;
            #pragma unroll
            for (int j = 0; j < 4; ++j)
                sm[j] += __expf(acc[j] * 0.125f + mrow[(size_t)j * kS + t]);
        }
        if (nxt) {
            *(u16x8*)((char*)k_sh[cur ^ 1] + kaddr_w) = cvt8(kf0, kf1);
            __syncthreads();
            cur ^= 1;
        }
    }
    #pragma unroll
    for (int j = 0; j < 4; ++j) {
        float s = sm[j];
        s += __shfl_xor(s, 1);
        s += __shfl_xor(s, 2);
        s += __shfl_xor(s, 4);
        s += __shfl_xor(s, 8);
        sm[j] = 1.0f / s;
    }

    f32x4 accO[4];
    #pragma unroll
    for (int dt = 0; dt < 4; ++dt) accO[dt] = f32x4{0.f, 0.f, 0.f, 0.f};

    __syncthreads();
    {
        *(u16x8*)((char*)k_sh[0] + kaddr_w) = cvt8(*(const float4*)kstage, *(const float4*)(kstage + 4));
        u16x8 vb = cvt8(*(const float4*)vstage, *(const float4*)(vstage + 4));
        #pragma unroll
        for (int i = 0; i < 8; ++i) {
            const int d = sc + i;
            const unsigned b = (unsigned)((d * 64 + sr * 2) ^ (((d >> 3) & 7) << 4));
            *(unsigned short*)((char*)vt_sh[0] + b) = vb[i];
        }
    }
    __syncthreads();

    const int wr = lane >> 3;
    const int wcb = lane & 7;
    float* wbase = Wg + ((size_t)(bh * kS + q0)) * kS;

    cur = 0;
    for (int t0 = 0; t0 < kS; t0 += 32) {
        const bool nxt = (t0 + 32) < kS;
        float4 kf0, kf1, vf0, vf1;
        if (nxt) {
            const float* srck = kstage + (size_t)(t0 + 32) * kD;
            kf0 = *(const float4*)srck; kf1 = *(const float4*)(srck + 4);
            const float* srcv = vstage + (size_t)(t0 + 32) * kD;
            vf0 = *(const float4*)srcv; vf1 = *(const float4*)(srcv + 4);
        }
        #pragma unroll
        for (int tt = 0; tt < 2; ++tt) {
            const int row = tt * 16 + c;
            f32x4 acc = {0.f, 0.f, 0.f, 0.f};
            #pragma unroll
            for (int h = 0; h < 2; ++h) {
                const unsigned a = (unsigned)((row * 128 + h * 64 + g * 16) ^ ((row & 7) << 4));
                s16x8 bK = *(const s16x8*)((const char*)k_sh[cur] + a);
                acc = __builtin_amdgcn_mfma_f32_16x16x32_bf16(aQ[h], bK, acc, 0, 0, 0);
            }
            const int t = t0 + tt * 16 + c;
            #pragma unroll
            for (int j = 0; j < 4; ++j) {
                const float p = __expf(acc[j] * 0.125f + mrow[(size_t)j * kS + t]) * sm[j];
                p_sh[wv][(g * 4 + j) * 40 + tt * 16 + c] = f2bf(p);
            }
        }

        s16x8 pa = *(const s16x8*)((const char*)&p_sh[wv][0] + c * 80 + g * 16);
        #pragma unroll
        for (int dt = 0; dt < 4; ++dt) {
            const int d = dt * 16 + c;
            const unsigned b = (unsigned)((d * 64 + g * 16) ^ (((d >> 3) & 7) << 4));
            s16x8 bV = *(const s16x8*)((const char*)vt_sh[cur] + b);
            accO[dt] = __builtin_amdgcn_mfma_f32_16x16x32_bf16(pa, bV, accO[dt], 0, 0, 0);
        }

        #pragma unroll
        for (int s = 0; s < 2; ++s) {
            const int row = wr + s * 8;
            u16x4 pb = *(const u16x4*)((const char*)&p_sh[wv][0] + row * 80 + wcb * 8);
            f32x4 w;
            #pragma unroll
            for (int i = 0; i < 4; ++i) w[i] = bf2f(pb[i]);
            __builtin_nontemporal_store(w, (f32x4*)(wbase + (size_t)row * kS + t0 + wcb * 4));
        }

        if (nxt) {
            *(u16x8*)((char*)k_sh[cur ^ 1] + kaddr_w) = cvt8(kf0, kf1);
            u16x8 vb = cvt8(vf0, vf1);
            #pragma unroll
            for (int i = 0; i < 8; ++i) {
                const int d = sc + i;
                const unsigned b = (unsigned)((d * 64 + sr * 2) ^ (((d >> 3) & 7) << 4));
                *(unsigned short*)((char*)vt_sh[cur ^ 1] + b) = vb[i];
            }
            __syncthreads();
            cur ^= 1;
        }
    }

    float* orow = Og + ((size_t)(bh * kS + q0 + g * 4)) * kD + c;
    #pragma unroll
    for (int dt = 0; dt < 4; ++dt) {
        #pragma unroll
        for (int j = 0; j < 4; ++j)
            __builtin_nontemporal_store(accO[dt][j], orow + (size_t)j * kD + dt * 16);
    }
}

extern "C" void kernel_launch(void* const* d_in, const int* in_sizes, int n_in,
                              void* d_out, int out_size, void* d_ws, size_t ws_size,
                              hipStream_t stream) {
    const float* q = (const float*)d_in[0];
    const float* k = (const float*)d_in[1];
    const float* v = (const float*)d_in[2];
    const float* m = (const float*)d_in[3];
    float* out = (float*)d_out;
    float* we  = out + OUT_ELEMS;

    const size_t need = (size_t)CVT_TOTAL * sizeof(unsigned short);  // 20 MB
    if (ws_size >= need) {
        unsigned short* wsb = (unsigned short*)d_ws;
        cvt_bf16<<<dim3(CVT_TOTAL / 8 / 256), dim3(256), 0, stream>>>(k, v, m, wsb);
        attn_fused_b<<<dim3(kBH * 32), dim3(256), 0, stream>>>(
            q, wsb, wsb + OUT_ELEMS, wsb + 2 * OUT_ELEMS, out, we);
    } else {
        attn_fused_f32<<<dim3(kBH * 32), dim3(256), 0, stream>>>(q, k, v, m, out, we);
    }
}

// Round 18
// 139.203 us; speedup vs baseline: 1.1031x; 1.1031x over previous
//
#include <hip/hip_runtime.h>

// Scaled dot-product attention, B=2 H=12 S=2048 D=64, fp32 in/out.
// Outputs: out [B,H,S,D] then we [B,H,S,S] concatenated in d_out.
// R17 = R15 (best 143.8us) + DEFERRED we-STORE: p_sh double-buffered;
// stage i's we lines are stored at stage i+1's top, giving each nt store
// a full stage (~2000cy) to retire before the barrier's vmcnt(0) (vmcnt
// is in-order, so the drain is unavoidable — R16 — but its EXPOSURE is
// schedulable). In-loop barriers are plain __syncthreads again.

typedef short          s16x8 __attribute__((ext_vector_type(8)));
typedef unsigned short u16x8 __attribute__((ext_vector_type(8)));
typedef unsigned short u16x4 __attribute__((ext_vector_type(4)));
typedef float          f32x4 __attribute__((ext_vector_type(4)));

#define kS   2048
#define kD   64
#define kBH  24
#define OUT_ELEMS (kBH * kS * kD)     // 3145728
#define MASK_ELEMS (kS * kS)          // 4194304
#define CVT_TOTAL (2 * OUT_ELEMS + MASK_ELEMS)   // 10485760

static __device__ __forceinline__ unsigned short f2bf(float f) {
    union { float f; unsigned u; } x; x.f = f;
    return (unsigned short)((x.u + 0x7fffu + ((x.u >> 16) & 1u)) >> 16); // RNE
}
static __device__ __forceinline__ float bf2f(unsigned short v) {
    union { unsigned u; float f; } x; x.u = ((unsigned)v) << 16;
    return x.f;
}
static __device__ __forceinline__ u16x8 cvt8(const float4 f0, const float4 f1) {
    u16x8 r;
    r[0] = f2bf(f0.x); r[1] = f2bf(f0.y); r[2] = f2bf(f0.z); r[3] = f2bf(f0.w);
    r[4] = f2bf(f1.x); r[5] = f2bf(f1.y); r[6] = f2bf(f1.z); r[7] = f2bf(f1.w);
    return r;
}

// ---------------- prologue: fp32 -> bf16 (K | V | mask) ----------------
__global__ __launch_bounds__(256)
void cvt_bf16(const float* __restrict__ K, const float* __restrict__ V,
              const float* __restrict__ M, unsigned short* __restrict__ W)
{
    const size_t e = ((size_t)blockIdx.x * 256 + threadIdx.x) * 8;
    if (e >= CVT_TOTAL) return;
    const float* src;
    size_t off;
    if (e < OUT_ELEMS)            { src = K; off = e; }
    else if (e < 2 * OUT_ELEMS)   { src = V; off = e - OUT_ELEMS; }
    else                          { src = M; off = e - 2 * OUT_ELEMS; }
    float4 a = *(const float4*)(src + off);
    float4 b = *(const float4*)(src + off + 4);
    *(u16x8*)(W + e) = cvt8(a, b);
}

// ---------------- main kernel (bf16 operands) ----------------
__global__ __launch_bounds__(256)
void attn_fused_b(const float* __restrict__ Qg, const unsigned short* __restrict__ Kb,
                  const unsigned short* __restrict__ Vb, const unsigned short* __restrict__ Mb,
                  float* __restrict__ Og, float* __restrict__ Wg)
{
    __shared__ __align__(16) unsigned short k_sh[2][32 * 64];
    __shared__ __align__(16) unsigned short vt_sh[2][64 * 32];
    __shared__ __align__(16) unsigned short p_sh[4][2][16 * 40];   // dbuf P

    const int tid  = threadIdx.x;
    const int wv   = tid >> 6;
    const int lane = tid & 63;
    const int g    = lane >> 4;
    const int c    = lane & 15;

    // head-partitioned XCD swizzle (R11): 768 blocks, 96/XCD = 3 heads/XCD
    const int wg = ((int)blockIdx.x & 7) * 96 + ((int)blockIdx.x >> 3);
    const int bh = wg >> 5;
    const int qb = wg & 31;
    const int q0 = qb * 64 + wv * 16;

    // Q A-fragments (row = q0+c, k = h*32+g*8+j), validated R2
    s16x8 aQ[2];
    {
        const float* qp = Qg + ((size_t)(bh * kS + q0 + c)) * kD + g * 8;
        #pragma unroll
        for (int h = 0; h < 2; ++h) {
            float4 f0 = *(const float4*)(qp + h * 32);
            float4 f1 = *(const float4*)(qp + h * 32 + 4);
            union { u16x8 u; s16x8 s; } t; t.u = cvt8(f0, f1);
            aQ[h] = t.s;
        }
    }

    const int sr = tid >> 3;
    const int sc = (tid & 7) * 8;
    const unsigned short* kstage = Kb + ((size_t)bh * kS + sr) * kD + sc;
    const unsigned short* vstage = Vb + ((size_t)bh * kS + sr) * kD + sc;
    const unsigned kaddr_w = (unsigned)((sr * 128 + sc * 2) ^ ((sr & 7) << 4));
    const unsigned short* mrow = Mb + (size_t)(q0 + g * 4) * kS;

    // ================= pass 1: softmax denominators =================
    {
        *(u16x8*)((char*)k_sh[0] + kaddr_w) = *(const u16x8*)kstage;
    }
    __syncthreads();

    float sm[4] = {0.f, 0.f, 0.f, 0.f};
    int cur = 0;
    for (int t0 = 0; t0 < kS; t0 += 32) {
        const bool nxt = (t0 + 32) < kS;
        u16x8 kf;
        if (nxt) kf = *(const u16x8*)(kstage + (size_t)(t0 + 32) * kD);
        #pragma unroll
        for (int tt = 0; tt < 2; ++tt) {
            const int row = tt * 16 + c;
            f32x4 acc = {0.f, 0.f, 0.f, 0.f};
            #pragma unroll
            for (int h = 0; h < 2; ++h) {
                const unsigned a = (unsigned)((row * 128 + h * 64 + g * 16) ^ ((row & 7) << 4));
                s16x8 bK = *(const s16x8*)((const char*)k_sh[cur] + a);
                acc = __builtin_amdgcn_mfma_f32_16x16x32_bf16(aQ[h], bK, acc, 0, 0, 0);
            }
            const int t = t0 + tt * 16 + c;
            #pragma unroll
            for (int j = 0; j < 4; ++j)
                sm[j] += __expf(acc[j] * 0.125f + bf2f(mrow[(size_t)j * kS + t]));
        }
        if (nxt) {
            *(u16x8*)((char*)k_sh[cur ^ 1] + kaddr_w) = kf;
            __syncthreads();
            cur ^= 1;
        }
    }
    #pragma unroll
    for (int j = 0; j < 4; ++j) {
        float s = sm[j];
        s += __shfl_xor(s, 1);
        s += __shfl_xor(s, 2);
        s += __shfl_xor(s, 4);
        s += __shfl_xor(s, 8);
        sm[j] = 1.0f / s;
    }

    // ================= pass 2: write we, accumulate PV =================
    f32x4 accO[4];
    #pragma unroll
    for (int dt = 0; dt < 4; ++dt) accO[dt] = f32x4{0.f, 0.f, 0.f, 0.f};

    __syncthreads();
    {
        *(u16x8*)((char*)k_sh[0] + kaddr_w) = *(const u16x8*)kstage;
        u16x8 vb = *(const u16x8*)vstage;
        #pragma unroll
        for (int i = 0; i < 8; ++i) {
            const int d = sc + i;
            const unsigned b = (unsigned)((d * 64 + sr * 2) ^ (((d >> 3) & 7) << 4));
            *(unsigned short*)((char*)vt_sh[0] + b) = vb[i];
        }
    }
    __syncthreads();

    const int wr = lane >> 3;
    const int wcb = lane & 7;
    float* wbase = Wg + ((size_t)(bh * kS + q0)) * kS;

    cur = 0;
    int pcur = 0;
    for (int t0 = 0; t0 < kS; t0 += 32) {
        const bool nxt = (t0 + 32) < kS;
        u16x8 kf, vf;
        if (nxt) {
            kf = *(const u16x8*)(kstage + (size_t)(t0 + 32) * kD);
            vf = *(const u16x8*)(vstage + (size_t)(t0 + 32) * kD);
        }

        // ---- deferred we-store of PREVIOUS tile (full stage to retire) ----
        if (t0 > 0) {
            #pragma unroll
            for (int s = 0; s < 2; ++s) {
                const int row = wr + s * 8;
                u16x4 pb = *(const u16x4*)((const char*)&p_sh[wv][pcur ^ 1][0] + row * 80 + wcb * 8);
                f32x4 w;
                #pragma unroll
                for (int i = 0; i < 4; ++i) w[i] = bf2f(pb[i]);
                __builtin_nontemporal_store(w, (f32x4*)(wbase + (size_t)row * kS + (t0 - 32) + wcb * 4));
            }
        }

        #pragma unroll
        for (int tt = 0; tt < 2; ++tt) {
            const int row = tt * 16 + c;
            f32x4 acc = {0.f, 0.f, 0.f, 0.f};
            #pragma unroll
            for (int h = 0; h < 2; ++h) {
                const unsigned a = (unsigned)((row * 128 + h * 64 + g * 16) ^ ((row & 7) << 4));
                s16x8 bK = *(const s16x8*)((const char*)k_sh[cur] + a);
                acc = __builtin_amdgcn_mfma_f32_16x16x32_bf16(aQ[h], bK, acc, 0, 0, 0);
            }
            const int t = t0 + tt * 16 + c;
            #pragma unroll
            for (int j = 0; j < 4; ++j) {
                const float p = __expf(acc[j] * 0.125f + bf2f(mrow[(size_t)j * kS + t])) * sm[j];
                p_sh[wv][pcur][(g * 4 + j) * 40 + tt * 16 + c] = f2bf(p);
            }
        }

        s16x8 pa = *(const s16x8*)((const char*)&p_sh[wv][pcur][0] + c * 80 + g * 16);
        #pragma unroll
        for (int dt = 0; dt < 4; ++dt) {
            const int d = dt * 16 + c;
            const unsigned b = (unsigned)((d * 64 + g * 16) ^ (((d >> 3) & 7) << 4));
            s16x8 bV = *(const s16x8*)((const char*)vt_sh[cur] + b);
            accO[dt] = __builtin_amdgcn_mfma_f32_16x16x32_bf16(pa, bV, accO[dt], 0, 0, 0);
        }

        if (nxt) {
            *(u16x8*)((char*)k_sh[cur ^ 1] + kaddr_w) = kf;
            #pragma unroll
            for (int i = 0; i < 8; ++i) {
                const int d = sc + i;
                const unsigned b = (unsigned)((d * 64 + sr * 2) ^ (((d >> 3) & 7) << 4));
                *(unsigned short*)((char*)vt_sh[cur ^ 1] + b) = vf[i];
            }
            __syncthreads();
            cur ^= 1;
        }
        pcur ^= 1;
    }

    // final tile's deferred we-store (p_sh is wave-private: no barrier needed)
    {
        #pragma unroll
        for (int s = 0; s < 2; ++s) {
            const int row = wr + s * 8;
            u16x4 pb = *(const u16x4*)((const char*)&p_sh[wv][pcur ^ 1][0] + row * 80 + wcb * 8);
            f32x4 w;
            #pragma unroll
            for (int i = 0; i < 4; ++i) w[i] = bf2f(pb[i]);
            __builtin_nontemporal_store(w, (f32x4*)(wbase + (size_t)row * kS + (kS - 32) + wcb * 4));
        }
    }

    float* orow = Og + ((size_t)(bh * kS + q0 + g * 4)) * kD + c;
    #pragma unroll
    for (int dt = 0; dt < 4; ++dt) {
        #pragma unroll
        for (int j = 0; j < 4; ++j)
            __builtin_nontemporal_store(accO[dt][j], orow + (size_t)j * kD + dt * 16);
    }
}

// ---------------- fallback: exact R11 (fp32 operands) ----------------
__global__ __launch_bounds__(256)
void attn_fused_f32(const float* __restrict__ Qg, const float* __restrict__ Kg,
                    const float* __restrict__ Vg, const float* __restrict__ Mg,
                    float* __restrict__ Og, float* __restrict__ Wg)
{
    __shared__ __align__(16) unsigned short k_sh[2][32 * 64];
    __shared__ __align__(16) unsigned short vt_sh[2][64 * 32];
    __shared__ __align__(16) unsigned short p_sh[4][16 * 40];

    const int tid  = threadIdx.x;
    const int wv   = tid >> 6;
    const int lane = tid & 63;
    const int g    = lane >> 4;
    const int c    = lane & 15;

    const int wg = ((int)blockIdx.x & 7) * 96 + ((int)blockIdx.x >> 3);
    const int bh = wg >> 5;
    const int qb = wg & 31;
    const int q0 = qb * 64 + wv * 16;

    s16x8 aQ[2];
    {
        const float* qp = Qg + ((size_t)(bh * kS + q0 + c)) * kD + g * 8;
        #pragma unroll
        for (int h = 0; h < 2; ++h) {
            float4 f0 = *(const float4*)(qp + h * 32);
            float4 f1 = *(const float4*)(qp + h * 32 + 4);
            union { u16x8 u; s16x8 s; } t; t.u = cvt8(f0, f1);
            aQ[h] = t.s;
        }
    }

    const int sr = tid >> 3;
    const int sc = (tid & 7) * 8;
    const float* kstage = Kg + ((size_t)bh * kS + sr) * kD + sc;
    const float* vstage = Vg + ((size_t)bh * kS + sr) * kD + sc;
    const unsigned kaddr_w = (unsigned)((sr * 128 + sc * 2) ^ ((sr & 7) << 4));
    const float* mrow = Mg + (size_t)(q0 + g * 4) * kS;

    {
        *(u16x8*)((char*)k_sh[0] + kaddr_w) = cvt8(*(const float4*)kstage, *(const float4*)(kstage + 4));
    }
    __syncthreads();

    float sm[4] = {0.f, 0.f, 0.f, 0.f};
    int cur = 0;
    for (int t0 = 0; t0 < kS; t0 += 32) {
        const bool nxt = (t0 + 32) < kS;
        float4 kf0, kf1;
        if (nxt) {
            const float* src = kstage + (size_t)(t0 + 32) * kD;
            kf0 = *(const float4*)src; kf1 = *(const float4*)(src + 4);
        }
        #pragma unroll
        for (int tt = 0; tt < 2; ++tt) {
            const int row = tt * 16 + c;
            f32x4 acc = {0.f, 0.f, 0.f, 0.f};
            #pragma unroll
            for (int h = 0; h < 2; ++h) {
                const unsigned a = (unsigned)((row * 128 + h * 64 + g * 16) ^ ((row & 7) << 4));
                s16x8 bK = *(const s16x8*)((const char*)k_sh[cur] + a);
                acc = __builtin_amdgcn_mfma_f32_16x16x32_bf16(aQ[h], bK, acc, 0, 0, 0);
            }
            const int t = t0 + tt * 16 + c;
            #pragma unroll
            for (int j = 0; j < 4; ++j)
                sm[j] += __expf(acc[j] * 0.125f + mrow[(size_t)j * kS + t]);
        }
        if (nxt) {
            *(u16x8*)((char*)k_sh[cur ^ 1] + kaddr_w) = cvt8(kf0, kf1);
            __syncthreads();
            cur ^= 1;
        }
    }
    #pragma unroll
    for (int j = 0; j < 4; ++j) {
        float s = sm[j];
        s += __shfl_xor(s, 1);
        s += __shfl_xor(s, 2);
        s += __shfl_xor(s, 4);
        s += __shfl_xor(s, 8);
        sm[j] = 1.0f / s;
    }

    f32x4 accO[4];
    #pragma unroll
    for (int dt = 0; dt < 4; ++dt) accO[dt] = f32x4{0.f, 0.f, 0.f, 0.f};

    __syncthreads();
    {
        *(u16x8*)((char*)k_sh[0] + kaddr_w) = cvt8(*(const float4*)kstage, *(const float4*)(kstage + 4));
        u16x8 vb = cvt8(*(const float4*)vstage, *(const float4*)(vstage + 4));
        #pragma unroll
        for (int i = 0; i < 8; ++i) {
            const int d = sc + i;
            const unsigned b = (unsigned)((d * 64 + sr * 2) ^ (((d >> 3) & 7) << 4));
            *(unsigned short*)((char*)vt_sh[0] + b) = vb[i];
        }
    }
    __syncthreads();

    const int wr = lane >> 3;
    const int wcb = lane & 7;
    float* wbase = Wg + ((size_t)(bh * kS + q0)) * kS;

    cur = 0;
    for (int t0 = 0; t0 < kS; t0 += 32) {
        const bool nxt = (t0 + 32) < kS;
        float4 kf0, kf1, vf0, vf1;
        if (nxt) {
            const float* srck = kstage + (size_t)(t0 + 32) * kD;
            kf0 = *(const float4*)srck; kf1 = *(const float4*)(srck + 4);
            const float* srcv = vstage + (size_t)(t0 + 32) * kD;
            vf0 = *(const float4*)srcv; vf1 = *(const float4*)(srcv + 4);
        }
        #pragma unroll
        for (int tt = 0; tt < 2; ++tt) {
            const int row = tt * 16 + c;
            f32x4 acc = {0.f, 0.f, 0.f, 0.f};
            #pragma unroll
            for (int h = 0; h < 2; ++h) {
                const unsigned a = (unsigned)((row * 128 + h * 64 + g * 16) ^ ((row & 7) << 4));
                s16x8 bK = *(const s16x8*)((const char*)k_sh[cur] + a);
                acc = __builtin_amdgcn_mfma_f32_16x16x32_bf16(aQ[h], bK, acc, 0, 0, 0);
            }
            const int t = t0 + tt * 16 + c;
            #pragma unroll
            for (int j = 0; j < 4; ++j) {
                const float p = __expf(acc[j] * 0.125f + mrow[(size_t)j * kS + t]) * sm[j];
                p_sh[wv][(g * 4 + j) * 40 + tt * 16 + c] = f2bf(p);
            }
        }

        s16x8 pa = *(const s16x8*)((const char*)&p_sh[wv][0] + c * 80 + g * 16);
        #pragma unroll
        for (int dt = 0; dt < 4; ++dt) {
            const int d = dt * 16 + c;
            const unsigned b = (unsigned)((d * 64 + g * 16) ^ (((d >> 3) & 7) << 4));
            s16x8 bV = *(const s16x8*)((const char*)vt_sh[cur] + b);
            accO[dt] = __builtin_amdgcn_mfma_f32_16x16x32_bf16(pa, bV, accO[dt], 0, 0, 0);
        }

        #pragma unroll
        for (int s = 0; s < 2; ++s) {
            const int row = wr + s * 8;
            u16x4 pb = *(const u16x4*)((const char*)&p_sh[wv][0] + row * 80 + wcb * 8);
            f32x4 w;
            #pragma unroll
            for (int i = 0; i < 4; ++i) w[i] = bf2f(pb[i]);
            __builtin_nontemporal_store(w, (f32x4*)(wbase + (size_t)row * kS + t0 + wcb * 4));
        }

        if (nxt) {
            *(u16x8*)((char*)k_sh[cur ^ 1] + kaddr_w) = cvt8(kf0, kf1);
            u16x8 vb = cvt8(vf0, vf1);
            #pragma unroll
            for (int i = 0; i < 8; ++i) {
                const int d = sc + i;
                const unsigned b = (unsigned)((d * 64 + sr * 2) ^ (((d >> 3) & 7) << 4));
                *(unsigned short*)((char*)vt_sh[cur ^ 1] + b) = vb[i];
            }
            __syncthreads();
            cur ^= 1;
        }
    }

    float* orow = Og + ((size_t)(bh * kS + q0 + g * 4)) * kD + c;
    #pragma unroll
    for (int dt = 0; dt < 4; ++dt) {
        #pragma unroll
        for (int j = 0; j < 4; ++j)
            __builtin_nontemporal_store(accO[dt][j], orow + (size_t)j * kD + dt * 16);
    }
}

extern "C" void kernel_launch(void* const* d_in, const int* in_sizes, int n_in,
                              void* d_out, int out_size, void* d_ws, size_t ws_size,
                              hipStream_t stream) {
    const float* q = (const float*)d_in[0];
    const float* k = (const float*)d_in[1];
    const float* v = (const float*)d_in[2];
    const float* m = (const float*)d_in[3];
    float* out = (float*)d_out;
    float* we  = out + OUT_ELEMS;

    const size_t need = (size_t)CVT_TOTAL * sizeof(unsigned short);  // 20 MB
    if (ws_size >= need) {
        unsigned short* wsb = (unsigned short*)d_ws;
        cvt_bf16<<<dim3(CVT_TOTAL / 8 / 256), dim3(256), 0, stream>>>(k, v, m, wsb);
        attn_fused_b<<<dim3(kBH * 32), dim3(256), 0, stream>>>(
            q, wsb, wsb + OUT_ELEMS, wsb + 2 * OUT_ELEMS, out, we);
    } else {
        attn_fused_f32<<<dim3(kBH * 32), dim3(256), 0, stream>>>(q, k, v, m, out, we);
    }
}